// Round 1
// baseline (513.638 us; speedup 1.0000x reference)
//
#include <hip/hip_runtime.h>
#include <math.h>

#define Bb   2
#define CIN  32
#define Gg   4
#define NH   4
#define Hh   28
#define Ww   28
#define HW   784
#define Pp   7
#define PP   49
#define MKL  196
#define MID  48
#define COUT 64
#define POSC 16
#define OC   192   // MID*NH

// workspace offsets (in floats)
#define QOFF  0
#define KOFF  1204224
#define VOFF  2408448
#define OOFF  3612672
#define PEOFF 4816896
#define GEOFF 4823168
// total = 4824192 floats = 19,296,768 bytes

// ---------------------------------------------------------------- kernel 0
// PE MLPs (row/col) -> pe[v][kl][32], group-emb gather -> ge[v][g][m][16]
__global__ void pe_kernel(const float* row_w1, const float* row_b1,
                          const float* row_g,  const float* row_bb,
                          const float* row_w2, const float* row_b2,
                          const float* col_w1, const float* col_b1,
                          const float* col_g,  const float* col_bb,
                          const float* col_w2, const float* col_b2,
                          const float* row_idx, const float* col_idx,
                          const float* group_emb, const int* g_indices,
                          float* ws)
{
    float* pe = ws + PEOFF;
    float* ge = ws + GEOFF;
    int tid = threadIdx.x;

    for (int t = tid; t < 2 * Gg * PP; t += blockDim.x) {
        int half = t / (Gg * PP);          // 0 = row, 1 = col
        int n    = t - half * (Gg * PP);   // v*49 + kl
        const float* w1 = half ? col_w1 : row_w1;
        const float* b1 = half ? col_b1 : row_b1;
        const float* lg = half ? col_g  : row_g;
        const float* lb = half ? col_bb : row_bb;
        const float* w2 = half ? col_w2 : row_w2;
        const float* b2 = half ? col_b2 : row_b2;
        float tv = half ? col_idx[n] : row_idx[n];

        float hb[16];
        float mean = 0.f;
        for (int k = 0; k < 16; k++) { hb[k] = tv * w1[k] + b1[k]; mean += hb[k]; }
        mean *= (1.f / 16.f);
        float var = 0.f;
        for (int k = 0; k < 16; k++) { float d = hb[k] - mean; var += d * d; }
        var *= (1.f / 16.f);
        float inv = 1.f / sqrtf(var + 1e-5f);
        for (int k = 0; k < 16; k++) {
            float hn = (hb[k] - mean) * inv * lg[k] + lb[k];
            hb[k] = hn / (1.f + expf(-hn));            // swish
        }
        for (int p = 0; p < POSC; p++) {
            float acc = b2[p];
            for (int k = 0; k < 16; k++) acc += hb[k] * w2[p * 16 + k];
            pe[n * 32 + half * POSC + p] = acc;
        }
    }

    for (int t = tid; t < Gg * Gg * Gg; t += blockDim.x) {
        int gi = g_indices[t];
        for (int c = 0; c < 16; c++) ge[t * 16 + c] = group_emb[gi * 16 + c];
    }
}

// ---------------------------------------------------------------- kernel 1
// fused QKV 1x1 conv: x (B,CIN,G,H,W) -> Q/K/V [b][h][g][ij][c]
__global__ void qkv_kernel(const float* __restrict__ x,
                           const float* __restrict__ Wq, const float* __restrict__ bq,
                           const float* __restrict__ Wk, const float* __restrict__ bk,
                           const float* __restrict__ Wv, const float* __restrict__ bv,
                           float* __restrict__ ws)
{
    __shared__ float xs[CIN];
    int blk = blockIdx.x;                  // (b*G + g)*HW + ij
    int ij  = blk % HW;
    int bg  = blk / HW;
    int g   = bg % Gg;
    int b   = bg / Gg;
    int tid = threadIdx.x;                 // 0..191

    if (tid < CIN) xs[tid] = x[((b * CIN + tid) * Gg + g) * HW + ij];
    __syncthreads();

    int o = tid;
    float aq = bq[o], ak = bk[o], av = bv[o];
    const float* wq = Wq + o * CIN;
    const float* wk = Wk + o * CIN;
    const float* wv = Wv + o * CIN;
    #pragma unroll
    for (int ci = 0; ci < CIN; ci++) {
        float xv = xs[ci];
        aq += wq[ci] * xv;
        ak += wk[ci] * xv;
        av += wv[ci] * xv;
    }
    int c = o >> 2, h = o & 3;             // o = c*NH + h
    int idx = (((b * NH + h) * Gg + g) * HW + ij) * MID + c;
    ws[QOFF + idx] = aq;
    ws[KOFF + idx] = ak;
    ws[VOFF + idx] = av;
}

// ---------------------------------------------------------------- kernel 2
// main attention: one wave per (b,h,i,j)
struct alignas(16) WaveShm {
    float qs[OC];          // [g][c] 192
    float cont[Gg * MKL];  // [g][e] 784
    float pp[Gg * MKL];    // [v][e] 784
    float pekl[52];
    float gsm[4];
};

__global__ __launch_bounds__(256) void attn_kernel(float* __restrict__ ws)
{
    __shared__ WaveShm shm[4];
    const int wave = threadIdx.x >> 6;
    const int lane = threadIdx.x & 63;
    WaveShm& S = shm[wave];

    int pos = blockIdx.x * 4 + wave;       // < B*NH*HW = 6272
    int ij  = pos % HW;
    int bh  = pos / HW;
    int h   = bh % NH;
    int b   = bh / NH;
    int i   = ij / Ww, j = ij % Ww;

    const float* Qt = ws + QOFF;
    const float* Kt = ws + KOFF;
    const float* Vt = ws + VOFF;
    const float* pe = ws + PEOFF;
    const float* ge = ws + GEOFF;
    float* Ot = ws + OOFF;

    const int bhbase = (b * NH + h) * Gg * HW * MID;

    // load q[g][c] and zero pp
    for (int t = lane; t < OC; t += 64) {
        int g = t / MID, c = t % MID;
        S.qs[t] = Qt[bhbase + (g * HW + ij) * MID + c];
    }
    for (int t = lane; t < Gg * MKL; t += 64) S.pp[t] = 0.f;
    __syncthreads();

    // content[g][m][k][l] = 48-dot(q[g], K[m, i+k-3, j+l-3])
    const float* Kbh = Kt + bhbase;
    for (int t = lane; t < Gg * MKL; t += 64) {
        int g  = t / MKL, e = t % MKL;
        int m  = e / PP,  kl = e % PP;
        int kk = kl / Pp, ll = kl % Pp;
        int y = i + kk - 3, x = j + ll - 3;
        float acc = 0.f;
        if ((unsigned)y < Hh && (unsigned)x < Ww) {
            const float4* kp = (const float4*)(Kbh + (m * HW + y * Ww + x) * MID);
            const float4* qp = (const float4*)(S.qs + g * MID);
            #pragma unroll
            for (int c4 = 0; c4 < MID / 4; c4++) {
                float4 a = qp[c4]; float4 kv = kp[c4];
                acc += a.x * kv.x + a.y * kv.y + a.z * kv.z + a.w * kv.w;
            }
        }
        S.cont[t] = acc;
    }

    const float inv_sqn = 0.17677669529663687f;   // 1/sqrt(CIN=32)

    for (int vg = 0; vg < 16; vg++) {
        int v = vg >> 2, g = vg & 3;
        __syncthreads();   // protect pekl/gsm reuse + (first iter) cont/pp visibility
        if (lane < PP) {
            const float* pev = pe + (v * PP + lane) * 32;
            const float* qg  = S.qs + g * MID;
            float acc = 0.f;
            #pragma unroll
            for (int c = 0; c < 32; c++) acc += qg[c] * pev[c];
            S.pekl[lane] = acc;
        }
        if (lane < Gg) {
            const float* gev = ge + ((v * Gg + g) * Gg + lane) * 16;
            const float* qg  = S.qs + g * MID + 32;
            float acc = 0.f;
            #pragma unroll
            for (int c = 0; c < 16; c++) acc += qg[c] * gev[c];
            S.gsm[lane] = acc;
        }
        __syncthreads();

        float sv[4];
        float mx = -INFINITY;
        #pragma unroll
        for (int s = 0; s < 4; s++) {
            int e = lane + s * 64;
            sv[s] = -INFINITY;
            if (e < MKL) {
                int m  = e / PP,  kl = e % PP;
                int kk = kl / Pp, ll = kl % Pp;
                int y = i + kk - 3, x = j + ll - 3;
                if ((unsigned)y < Hh && (unsigned)x < Ww)
                    sv[s] = (S.cont[g * MKL + e] + S.pekl[kl] + S.gsm[m]) * inv_sqn;
            }
            mx = fmaxf(mx, sv[s]);
        }
        #pragma unroll
        for (int o = 32; o > 0; o >>= 1) mx = fmaxf(mx, __shfl_xor(mx, o, 64));

        float ex[4];
        float lsum = 0.f;
        #pragma unroll
        for (int s = 0; s < 4; s++) {
            ex[s] = (sv[s] == -INFINITY) ? 0.f : expf(sv[s] - mx);
            lsum += ex[s];
        }
        #pragma unroll
        for (int o = 32; o > 0; o >>= 1) lsum += __shfl_xor(lsum, o, 64);
        float inv = 1.f / lsum;

        #pragma unroll
        for (int s = 0; s < 4; s++) {
            int e = lane + s * 64;
            if (e < MKL) S.pp[v * MKL + e] += ex[s] * inv;
        }
    }
    __syncthreads();

    // o[v][c] = sum_e pp[v][e] * V[m,y,x,c]; each lane does 3 outputs
    const float* Vbh = Vt + bhbase;
    float acc[3] = {0.f, 0.f, 0.f};
    int vs[3], cs[3];
    #pragma unroll
    for (int s = 0; s < 3; s++) { int t = lane + s * 64; vs[s] = t / MID; cs[s] = t % MID; }

    for (int m = 0; m < Gg; m++) {
        const float* Vm = Vbh + m * HW * MID;
        int e = m * PP;
        for (int kk = 0; kk < Pp; kk++) {
            int y = i + kk - 3;
            if ((unsigned)y >= Hh) { e += Pp; continue; }
            for (int ll = 0; ll < Pp; ll++, e++) {
                int x = j + ll - 3;
                if ((unsigned)x >= Ww) continue;
                const float* vp = Vm + (y * Ww + x) * MID;
                #pragma unroll
                for (int s = 0; s < 3; s++)
                    acc[s] += S.pp[vs[s] * MKL + e] * vp[cs[s]];
            }
        }
    }

    #pragma unroll
    for (int s = 0; s < 3; s++) {
        int v = vs[s], c = cs[s];
        Ot[((b * Gg + v) * HW + ij) * OC + c * NH + h] = acc[s];
    }
}

// ---------------------------------------------------------------- kernel 3
// out[b,o,v,i,j] = bout[o] + sum_t Wout[o,t] * O[b,v,ij,t]
__global__ void outproj_kernel(const float* __restrict__ Wout,
                               const float* __restrict__ bout,
                               const float* __restrict__ ws,
                               float* __restrict__ out)
{
    __shared__ float ov[4][OC];
    int wave = threadIdx.x >> 6, lane = threadIdx.x & 63;
    int p = blockIdx.x * 4 + wave;         // (b*G + v)*HW + ij, < 6272
    const float* Ot = ws + OOFF;

    for (int t = lane; t < OC; t += 64) ov[wave][t] = Ot[p * OC + t];
    __syncthreads();

    float acc = bout[lane];
    const float* wrow = Wout + lane * OC;
    #pragma unroll 4
    for (int t = 0; t < OC; t++) acc += wrow[t] * ov[wave][t];

    int ij = p % HW;
    int bv = p / HW;
    int v  = bv % Gg;
    int b  = bv / Gg;
    out[((b * COUT + lane) * Gg + v) * HW + ij] = acc;
}

// ---------------------------------------------------------------- launch
extern "C" void kernel_launch(void* const* d_in, const int* in_sizes, int n_in,
                              void* d_out, int out_size, void* d_ws, size_t ws_size,
                              hipStream_t stream)
{
    const float* x      = (const float*)d_in[0];
    const float* Wq     = (const float*)d_in[1];
    const float* bq     = (const float*)d_in[2];
    const float* Wk     = (const float*)d_in[3];
    const float* bk     = (const float*)d_in[4];
    const float* Wv     = (const float*)d_in[5];
    const float* bv     = (const float*)d_in[6];
    const float* Wout   = (const float*)d_in[7];
    const float* bout   = (const float*)d_in[8];
    const float* row_w1 = (const float*)d_in[9];
    const float* row_b1 = (const float*)d_in[10];
    const float* row_g  = (const float*)d_in[11];
    const float* row_bb = (const float*)d_in[12];
    const float* row_w2 = (const float*)d_in[13];
    const float* row_b2 = (const float*)d_in[14];
    const float* col_w1 = (const float*)d_in[15];
    const float* col_b1 = (const float*)d_in[16];
    const float* col_g  = (const float*)d_in[17];
    const float* col_bb = (const float*)d_in[18];
    const float* col_w2 = (const float*)d_in[19];
    const float* col_b2 = (const float*)d_in[20];
    const float* gemb   = (const float*)d_in[21];
    const float* ridx   = (const float*)d_in[22];
    const float* cidx   = (const float*)d_in[23];
    const int*   gidx   = (const int*)d_in[24];

    float* ws  = (float*)d_ws;
    float* out = (float*)d_out;

    pe_kernel<<<1, 256, 0, stream>>>(row_w1, row_b1, row_g, row_bb, row_w2, row_b2,
                                     col_w1, col_b1, col_g, col_bb, col_w2, col_b2,
                                     ridx, cidx, gemb, gidx, ws);
    qkv_kernel<<<Bb * Gg * HW, 192, 0, stream>>>(x, Wq, bq, Wk, bk, Wv, bv, ws);
    attn_kernel<<<Bb * NH * HW / 4, 256, 0, stream>>>(ws);
    outproj_kernel<<<Bb * Gg * HW / 4, 256, 0, stream>>>(Wout, bout, ws, out);
}

// Round 2
// 292.312 us; speedup vs baseline: 1.7572x; 1.7572x over previous
//
#include <hip/hip_runtime.h>
#include <math.h>

#define Bb   2
#define CIN  32
#define Gg   4
#define NH   4
#define Hh   28
#define Ww   28
#define HW   784
#define Pp   7
#define PP   49
#define MKL  196
#define MID  48
#define COUT 64
#define OC   192   // MID*NH

// workspace offsets (floats); total 4,816,896 floats = 19.27 MB (< round-1 usage)
#define QOFF  0
#define KOFF  1204224
#define VOFF  2408448
#define OOFF  3612672

// small precomputed tables live in device globals (recomputed every call)
__device__ float g_peT[Gg * 32 * PP];   // [v][c(0..31)][kl]
__device__ float g_geT[16 * 64];        // [c][v*16+g*4+m]
__device__ float g_WT2[OC * COUT];      // [h*48+c][o], permuted Wout

// ---------------------------------------------------------------- kernel 0
__global__ void pe_kernel(const float* row_w1, const float* row_b1,
                          const float* row_g,  const float* row_bb,
                          const float* row_w2, const float* row_b2,
                          const float* col_w1, const float* col_b1,
                          const float* col_g,  const float* col_bb,
                          const float* col_w2, const float* col_b2,
                          const float* row_idx, const float* col_idx,
                          const float* group_emb, const int* g_indices,
                          const float* Wout)
{
    int tid = threadIdx.x;

    for (int t = tid; t < 2 * Gg * PP; t += blockDim.x) {
        int half = t / (Gg * PP);
        int n    = t - half * (Gg * PP);      // v*49 + kl
        int v = n / PP, kl = n % PP;
        const float* w1 = half ? col_w1 : row_w1;
        const float* b1 = half ? col_b1 : row_b1;
        const float* lg = half ? col_g  : row_g;
        const float* lb = half ? col_bb : row_bb;
        const float* w2 = half ? col_w2 : row_w2;
        const float* b2 = half ? col_b2 : row_b2;
        float tv = half ? col_idx[n] : row_idx[n];

        float hb[16];
        float mean = 0.f;
        for (int k = 0; k < 16; k++) { hb[k] = tv * w1[k] + b1[k]; mean += hb[k]; }
        mean *= (1.f / 16.f);
        float var = 0.f;
        for (int k = 0; k < 16; k++) { float d = hb[k] - mean; var += d * d; }
        var *= (1.f / 16.f);
        float inv = 1.f / sqrtf(var + 1e-5f);
        for (int k = 0; k < 16; k++) {
            float hn = (hb[k] - mean) * inv * lg[k] + lb[k];
            hb[k] = hn / (1.f + expf(-hn));
        }
        for (int p = 0; p < 16; p++) {
            float acc = b2[p];
            for (int k = 0; k < 16; k++) acc += hb[k] * w2[p * 16 + k];
            g_peT[(v * 32 + half * 16 + p) * PP + kl] = acc;
        }
    }

    for (int t = tid; t < 64; t += blockDim.x) {
        int gi = g_indices[t];
        for (int c = 0; c < 16; c++) g_geT[c * 64 + t] = group_emb[gi * 16 + c];
    }

    for (int idx = tid; idx < OC * COUT; idx += blockDim.x) {
        int tp = idx >> 6, o = idx & 63;      // tp = h*48+c
        int h = tp / MID, c = tp % MID;
        g_WT2[idx] = Wout[o * OC + c * NH + h];
    }
}

// ---------------------------------------------------------------- kernel 1
// Q/V row-major [bh][g][ij][c], K channel-major [bh][g][c][ij]
__global__ __launch_bounds__(192) void qkv_kernel(const float* __restrict__ x,
    const float* __restrict__ Wq, const float* __restrict__ bq,
    const float* __restrict__ Wk, const float* __restrict__ bk,
    const float* __restrict__ Wv, const float* __restrict__ bv,
    float* __restrict__ ws)
{
    __shared__ float xs[CIN * 14];
    __shared__ float kt[OC * 15];
    int tid = threadIdx.x;
    int blk = blockIdx.x;
    int jh = blk & 1; int r = blk >> 1;
    int i = r % Hh; r /= Hh;
    int g = r & 3; int b = r >> 2;
    int j0 = jh * 14;

    for (int idx = tid; idx < CIN * 14; idx += 192) {
        int ci = idx / 14, jj = idx % 14;
        xs[idx] = x[((b * CIN + ci) * Gg + g) * HW + i * Ww + j0 + jj];
    }
    __syncthreads();

    int o = tid, c = o >> 2, h = o & 3;
    float a[14];

    // ---- K (via LDS transpose to channel-major) ----
    {
        float w[CIN];
        #pragma unroll
        for (int ci = 0; ci < CIN; ci++) w[ci] = Wk[o * CIN + ci];
        float bias = bk[o];
        #pragma unroll
        for (int jj = 0; jj < 14; jj++) a[jj] = bias;
        for (int ci = 0; ci < CIN; ci++) {
            float wv = w[ci];
            #pragma unroll
            for (int jj = 0; jj < 14; jj++) a[jj] += wv * xs[ci * 14 + jj];
        }
        #pragma unroll
        for (int jj = 0; jj < 14; jj++) kt[o * 15 + jj] = a[jj];
    }
    __syncthreads();
    for (int idx = tid; idx < OC * 14; idx += 192) {
        int h2 = idx / (MID * 14); int r2 = idx % (MID * 14);
        int c2 = r2 / 14, jj = r2 % 14;
        ws[KOFF + (((b * NH + h2) * Gg + g) * MID + c2) * HW + i * Ww + j0 + jj]
            = kt[(c2 * NH + h2) * 15 + jj];
    }

    // ---- Q ----
    {
        float w[CIN];
        #pragma unroll
        for (int ci = 0; ci < CIN; ci++) w[ci] = Wq[o * CIN + ci];
        float bias = bq[o];
        #pragma unroll
        for (int jj = 0; jj < 14; jj++) a[jj] = bias;
        for (int ci = 0; ci < CIN; ci++) {
            float wv = w[ci];
            #pragma unroll
            for (int jj = 0; jj < 14; jj++) a[jj] += wv * xs[ci * 14 + jj];
        }
        int base = (((b * NH + h) * Gg + g) * HW + i * Ww + j0) * MID + c;
        #pragma unroll
        for (int jj = 0; jj < 14; jj++) ws[QOFF + base + jj * MID] = a[jj];
    }

    // ---- V ----
    {
        float w[CIN];
        #pragma unroll
        for (int ci = 0; ci < CIN; ci++) w[ci] = Wv[o * CIN + ci];
        float bias = bv[o];
        #pragma unroll
        for (int jj = 0; jj < 14; jj++) a[jj] = bias;
        for (int ci = 0; ci < CIN; ci++) {
            float wv = w[ci];
            #pragma unroll
            for (int jj = 0; jj < 14; jj++) a[jj] += wv * xs[ci * 14 + jj];
        }
        int base = (((b * NH + h) * Gg + g) * HW + i * Ww + j0) * MID + c;
        #pragma unroll
        for (int jj = 0; jj < 14; jj++) ws[VOFF + base + jj * MID] = a[jj];
    }
}

// ---------------------------------------------------------------- kernel 2
// one 64-thread block per (b,h,ij); no inter-wave coupling
__global__ __launch_bounds__(64) void attn_kernel(float* __restrict__ ws)
{
    __shared__ __align__(16) float qs2[OC];     // [c][g], pre-scaled
    __shared__ float cont[Gg * MKL];            // [g][e]
    __shared__ float pes[16 * PP];              // [v*4+g][kl]
    __shared__ float gsm[64];                   // [v*16+g*4+m]
    __shared__ float pp[Gg * MKL];              // [v][e]

    int lane = threadIdx.x;
    int pos  = blockIdx.x;                      // (b*NH+h)*HW + ij
    int ij = pos % HW; int bh = pos / HW;
    int h = bh & 3, b = bh >> 2;
    int i = ij / Ww, j = ij % Ww;

    const float* Qt  = ws + QOFF;
    const float* Kbh = ws + KOFF + (size_t)bh * Gg * MID * HW;
    const float* Vbh = ws + VOFF + (size_t)bh * Gg * HW * MID;
    float* Ot = ws + OOFF;

    const float scale = 0.17677669529663687f;   // 1/sqrt(32)
    #pragma unroll
    for (int s = 0; s < 3; s++) {
        int t = lane + 64 * s; int c = t >> 2, g = t & 3;
        qs2[t] = scale * Qt[((bh * Gg + g) * HW + ij) * MID + c];
    }
    __syncthreads();

    // per-s patch geometry (e = lane + 64s)
    int kl_[4], m_[4], off_[4]; bool val_[4]; int e_[4];
    #pragma unroll
    for (int s = 0; s < 4; s++) {
        int e = lane + 64 * s;
        int ec = e < MKL ? e : 0;
        int m = ec / PP, kl = ec % PP;
        int kk = kl / Pp, ll = kl % Pp;
        int y = i + kk - 3, xx = j + ll - 3;
        bool v = (e < MKL) && ((unsigned)y < Hh) && ((unsigned)xx < Ww);
        e_[s] = e; kl_[s] = kl; m_[s] = m; val_[s] = v;
        off_[s] = v ? (m * MID * HW + y * Ww + xx) : 0;
    }

    // content: coalesced channel-major K, all 4 g per load
    float acc[4][4];
    #pragma unroll
    for (int s = 0; s < 4; s++) { acc[s][0]=0; acc[s][1]=0; acc[s][2]=0; acc[s][3]=0; }
    const float4* qs4 = (const float4*)qs2;
    for (int c = 0; c < MID; c++) {
        float4 q4 = qs4[c];
        #pragma unroll
        for (int s = 0; s < 4; s++) {
            float kv = Kbh[off_[s] + c * HW];
            acc[s][0] += kv * q4.x; acc[s][1] += kv * q4.y;
            acc[s][2] += kv * q4.z; acc[s][3] += kv * q4.w;
        }
    }
    #pragma unroll
    for (int s = 0; s < 4; s++) if (e_[s] < MKL) {
        #pragma unroll
        for (int g = 0; g < 4; g++) cont[g * MKL + e_[s]] = acc[s][g];
    }

    // pe scores for all 16 (v,g): lanes = kl, coalesced peT reads
    if (lane < PP) {
        float pa[4][4];
        #pragma unroll
        for (int v = 0; v < 4; v++) { pa[v][0]=0; pa[v][1]=0; pa[v][2]=0; pa[v][3]=0; }
        for (int c = 0; c < 32; c++) {
            float4 q4 = qs4[c];
            #pragma unroll
            for (int v = 0; v < 4; v++) {
                float pk = g_peT[(v * 32 + c) * PP + lane];
                pa[v][0] += pk * q4.x; pa[v][1] += pk * q4.y;
                pa[v][2] += pk * q4.z; pa[v][3] += pk * q4.w;
            }
        }
        #pragma unroll
        for (int v = 0; v < 4; v++)
            #pragma unroll
            for (int g = 0; g < 4; g++)
                pes[(v * 4 + g) * PP + lane] = pa[v][g];
    }

    // group scores: lane = (v,g,m)
    {
        int g = (lane >> 2) & 3;
        float ga = 0.f;
        #pragma unroll
        for (int c = 0; c < 16; c++) ga += g_geT[c * 64 + lane] * qs2[(32 + c) * 4 + g];
        gsm[lane] = ga;
    }
    __syncthreads();

    // per-(v,g) softmax, accumulate prob-sums over g in registers
    float ppr[4][4];
    #pragma unroll
    for (int v = 0; v < 4; v++) { ppr[v][0]=0; ppr[v][1]=0; ppr[v][2]=0; ppr[v][3]=0; }
    #pragma unroll
    for (int v = 0; v < 4; v++) {
        #pragma unroll
        for (int g = 0; g < 4; g++) {
            int vg = v * 4 + g;
            float sv[4]; float mx = -INFINITY;
            #pragma unroll
            for (int s = 0; s < 4; s++) {
                int ec = e_[s] < MKL ? e_[s] : 0;
                float t = cont[g * MKL + ec] + pes[vg * PP + kl_[s]] + gsm[vg * 4 + m_[s]];
                sv[s] = val_[s] ? t : -INFINITY;
                mx = fmaxf(mx, sv[s]);
            }
            #pragma unroll
            for (int d = 32; d > 0; d >>= 1) mx = fmaxf(mx, __shfl_xor(mx, d, 64));
            float ex[4]; float ls = 0.f;
            #pragma unroll
            for (int s = 0; s < 4; s++) { ex[s] = __expf(sv[s] - mx); ls += ex[s]; }
            #pragma unroll
            for (int d = 32; d > 0; d >>= 1) ls += __shfl_xor(ls, d, 64);
            float rinv = 1.0f / ls;
            #pragma unroll
            for (int s = 0; s < 4; s++) ppr[v][s] += ex[s] * rinv;
        }
    }
    #pragma unroll
    for (int v = 0; v < 4; v++)
        #pragma unroll
        for (int s = 0; s < 4; s++)
            if (e_[s] < MKL) pp[v * MKL + e_[s]] = ppr[v][s];
    __syncthreads();

    // PV: lane = (v, c4); float4 V loads, scalar-uniform border branches
    int vv = lane / 12; if (vv > 3) vv = 3;
    int c4 = lane % 12;
    float4 oacc = {0.f, 0.f, 0.f, 0.f};
    for (int m = 0; m < Gg; m++) {
        for (int kk = 0; kk < Pp; kk++) {
            int y = i + kk - 3;
            if ((unsigned)y >= Hh) continue;
            #pragma unroll
            for (int ll = 0; ll < Pp; ll++) {
                int xx = j + ll - 3;
                if ((unsigned)xx >= Ww) continue;
                int e = m * PP + kk * Pp + ll;
                float p = pp[vv * MKL + e];
                const float4 v4 = *(const float4*)&Vbh[(m * HW + y * Ww + xx) * MID + c4 * 4];
                oacc.x += p * v4.x; oacc.y += p * v4.y;
                oacc.z += p * v4.z; oacc.w += p * v4.w;
            }
        }
    }
    if (lane < 48)
        *(float4*)&Ot[((b * Gg + vv) * HW + ij) * OC + h * MID + c4 * 4] = oacc;
}

// ---------------------------------------------------------------- kernel 3
__global__ __launch_bounds__(256) void outproj_kernel(const float* __restrict__ bout,
                                                      const float* __restrict__ ws,
                                                      float* __restrict__ out)
{
    __shared__ float ov[16 * 193];
    __shared__ float res[64 * 17];
    int tid = threadIdx.x;
    int p0 = blockIdx.x * 16;
    const float* Ot = ws + OOFF;

    for (int idx = tid; idx < 16 * OC; idx += 256) {
        int pl = idx / OC, t = idx % OC;
        ov[pl * 193 + t] = Ot[(size_t)(p0 + pl) * OC + t];
    }
    __syncthreads();

    int o = tid & 63, pg = tid >> 6;
    float a0 = bout[o], a1 = a0, a2 = a0, a3 = a0;
    for (int t = 0; t < OC; t++) {
        float w = g_WT2[t * 64 + o];
        a0 += w * ov[(pg     ) * 193 + t];
        a1 += w * ov[(pg +  4) * 193 + t];
        a2 += w * ov[(pg +  8) * 193 + t];
        a3 += w * ov[(pg + 12) * 193 + t];
    }
    res[o * 17 + pg     ] = a0;
    res[o * 17 + pg +  4] = a1;
    res[o * 17 + pg +  8] = a2;
    res[o * 17 + pg + 12] = a3;
    __syncthreads();

    for (int idx = tid; idx < 1024; idx += 256) {
        int o2 = idx >> 4, pl = idx & 15;
        int p = p0 + pl;
        int ij2 = p % HW; int bv = p / HW; int v = bv & 3; int bb = bv >> 2;
        out[((bb * COUT + o2) * Gg + v) * HW + ij2] = res[o2 * 17 + pl];
    }
}

// ---------------------------------------------------------------- launch
extern "C" void kernel_launch(void* const* d_in, const int* in_sizes, int n_in,
                              void* d_out, int out_size, void* d_ws, size_t ws_size,
                              hipStream_t stream)
{
    const float* x      = (const float*)d_in[0];
    const float* Wq     = (const float*)d_in[1];
    const float* bq     = (const float*)d_in[2];
    const float* Wk     = (const float*)d_in[3];
    const float* bk     = (const float*)d_in[4];
    const float* Wv     = (const float*)d_in[5];
    const float* bv     = (const float*)d_in[6];
    const float* Wout   = (const float*)d_in[7];
    const float* bout   = (const float*)d_in[8];
    const float* row_w1 = (const float*)d_in[9];
    const float* row_b1 = (const float*)d_in[10];
    const float* row_g  = (const float*)d_in[11];
    const float* row_bb = (const float*)d_in[12];
    const float* row_w2 = (const float*)d_in[13];
    const float* row_b2 = (const float*)d_in[14];
    const float* col_w1 = (const float*)d_in[15];
    const float* col_b1 = (const float*)d_in[16];
    const float* col_g  = (const float*)d_in[17];
    const float* col_bb = (const float*)d_in[18];
    const float* col_w2 = (const float*)d_in[19];
    const float* col_b2 = (const float*)d_in[20];
    const float* gemb   = (const float*)d_in[21];
    const float* ridx   = (const float*)d_in[22];
    const float* cidx   = (const float*)d_in[23];
    const int*   gidx   = (const int*)d_in[24];

    float* ws  = (float*)d_ws;
    float* out = (float*)d_out;

    pe_kernel<<<1, 256, 0, stream>>>(row_w1, row_b1, row_g, row_bb, row_w2, row_b2,
                                     col_w1, col_b1, col_g, col_bb, col_w2, col_b2,
                                     ridx, cidx, gemb, gidx, Wout);
    qkv_kernel<<<Bb * Gg * Hh * 2, 192, 0, stream>>>(x, Wq, bq, Wk, bk, Wv, bv, ws);
    attn_kernel<<<Bb * NH * HW, 64, 0, stream>>>(ws);
    outproj_kernel<<<Bb * Gg * HW / 16, 256, 0, stream>>>(bout, ws, out);
}

// Round 3
// 237.629 us; speedup vs baseline: 2.1615x; 1.2301x over previous
//
#include <hip/hip_runtime.h>
#include <math.h>

#define Bb   2
#define CIN  32
#define Gg   4
#define NH   4
#define Hh   28
#define Ww   28
#define HW   784
#define Pp   7
#define PP   49
#define MKL  196
#define MID  48
#define COUT 64
#define OC   192   // MID*NH

// workspace offsets (floats); Q/K/V/O all [bh][g][ij][c] row-major
#define QOFF  0
#define KOFF  1204224
#define VOFF  2408448
#define OOFF  3612672

// small precomputed tables (recomputed every call by the table block of qkvpe)
__device__ float g_peT[Gg * 32 * PP];   // [v][c(0..31)][kl]
__device__ float g_geT[16 * 64];        // [c][v*16+g*4+m]
__device__ float g_WT2[OC * COUT];      // [h*48+c][o], permuted Wout

// ---------------------------------------------------------------- kernel 1
// fused QKV 1x1 conv (blocks 0..223) + table setup (block 224)
__global__ __launch_bounds__(192) void qkvpe_kernel(const float* __restrict__ x,
    const float* __restrict__ Wq, const float* __restrict__ bq,
    const float* __restrict__ Wk, const float* __restrict__ bk,
    const float* __restrict__ Wv, const float* __restrict__ bv,
    const float* row_w1, const float* row_b1,
    const float* row_g,  const float* row_bb,
    const float* row_w2, const float* row_b2,
    const float* col_w1, const float* col_b1,
    const float* col_g,  const float* col_bb,
    const float* col_w2, const float* col_b2,
    const float* row_idx, const float* col_idx,
    const float* group_emb, const int* g_indices,
    const float* Wout,
    float* __restrict__ ws)
{
    int tid = threadIdx.x;
    if (blockIdx.x == Bb * Gg * Hh) {
        // ---------------- table block ----------------
        for (int t = tid; t < 2 * Gg * PP; t += 192) {
            int half = t / (Gg * PP);
            int n    = t - half * (Gg * PP);      // v*49 + kl
            int v = n / PP, kl = n % PP;
            const float* w1 = half ? col_w1 : row_w1;
            const float* b1 = half ? col_b1 : row_b1;
            const float* lg = half ? col_g  : row_g;
            const float* lb = half ? col_bb : row_bb;
            const float* w2 = half ? col_w2 : row_w2;
            const float* b2 = half ? col_b2 : row_b2;
            float tv = half ? col_idx[n] : row_idx[n];

            float hb[16];
            float mean = 0.f;
            for (int k = 0; k < 16; k++) { hb[k] = tv * w1[k] + b1[k]; mean += hb[k]; }
            mean *= (1.f / 16.f);
            float var = 0.f;
            for (int k = 0; k < 16; k++) { float d = hb[k] - mean; var += d * d; }
            var *= (1.f / 16.f);
            float inv = 1.f / sqrtf(var + 1e-5f);
            for (int k = 0; k < 16; k++) {
                float hn = (hb[k] - mean) * inv * lg[k] + lb[k];
                hb[k] = hn / (1.f + expf(-hn));
            }
            for (int p = 0; p < 16; p++) {
                float acc = b2[p];
                for (int k = 0; k < 16; k++) acc += hb[k] * w2[p * 16 + k];
                g_peT[(v * 32 + half * 16 + p) * PP + kl] = acc;
            }
        }
        for (int t = tid; t < 64; t += 192) {
            int gi = g_indices[t];
            for (int c = 0; c < 16; c++) g_geT[c * 64 + t] = group_emb[gi * 16 + c];
        }
        for (int idx = tid; idx < OC * COUT; idx += 192) {
            int tp = idx >> 6, o = idx & 63;      // tp = h*48+c
            int h = tp / MID, c = tp % MID;
            g_WT2[idx] = Wout[o * OC + c * NH + h];
        }
        return;
    }

    // ---------------- QKV block: one (b,g,i) row of 28 ----------------
    __shared__ float xs[CIN * Ww];
    int r = blockIdx.x;
    int i = r % Hh; r /= Hh;
    int g = r & 3;  int b = r >> 2;

    for (int idx = tid; idx < CIN * Ww; idx += 192)
        xs[idx] = x[((b * CIN + idx / Ww) * Gg + g) * HW + i * Ww + (idx % Ww)];
    __syncthreads();

    int h = tid / MID, c = tid % MID;
    int oo = c * NH + h;                          // original channel index
    int wbase = (((b * NH + h) * Gg + g) * HW + i * Ww) * MID + c;

    const float* Wm[3] = {Wq, Wk, Wv};
    const float* bm[3] = {bq, bk, bv};
    const int    off[3] = {QOFF, KOFF, VOFF};
    for (int p = 0; p < 3; p++) {
        float w[CIN];
        #pragma unroll
        for (int ci = 0; ci < CIN; ci++) w[ci] = Wm[p][oo * CIN + ci];
        float bias = bm[p][oo];
        float a[Ww];
        #pragma unroll
        for (int j = 0; j < Ww; j++) a[j] = bias;
        for (int ci = 0; ci < CIN; ci++) {
            float wv = w[ci];
            #pragma unroll
            for (int j = 0; j < Ww; j++) a[j] += wv * xs[ci * Ww + j];
        }
        #pragma unroll
        for (int j = 0; j < Ww; j++) ws[off[p] + wbase + j * MID] = a[j];
    }
}

// ---------------------------------------------------------------- kernel 2
// attention: block = 4 waves = positions (i, j0..j0+3) for one (b,h).
// K/V neighborhood tile staged per-m into LDS; content in registers.
#define CSTR 52                       // padded floats per (y,x) cell
__global__ __launch_bounds__(256) void attn_kernel(float* __restrict__ ws)
{
    __shared__ __align__(16) float  kvt[7 * 10 * CSTR];     // 14560 B
    __shared__ __align__(16) float4 pp4[4][MKL];            // 12544 B  [wave][e] -> 4 v's
    __shared__ float pes[4][16 * PP];                       // 12544 B  [wave][vg*49+kl]
    __shared__ __align__(16) float qs[4][OC];               //  3072 B  [wave][g*48+c] (pre-scaled)
    __shared__ float gsm[4][64];                            //  1024 B  [wave][vg*4+m]

    const int wave = threadIdx.x >> 6;
    const int lane = threadIdx.x & 63;

    int blk = blockIdx.x;                  // ((bh)*28 + i)*7 + j0/4
    int j0 = (blk % 7) * 4;
    int i  = (blk / 7) % Hh;
    int bh = blk / (7 * Hh);
    int b = bh >> 2, h = bh & 3;
    int j  = j0 + wave;
    int ij = i * Ww + j;

    const float* Qt  = ws + QOFF;
    const float* Kbh = ws + KOFF + (size_t)bh * Gg * HW * MID;
    const float* Vbh = ws + VOFF + (size_t)bh * Gg * HW * MID;
    float* Ot = ws + OOFF;

    // ---- load q (scaled) into per-wave LDS ----
    const float scale = 0.17677669529663687f;   // 1/sqrt(32)
    #pragma unroll
    for (int s = 0; s < 3; s++) {
        int t = lane + 64 * s;                  // t = g*48+c
        qs[wave][t] = scale * Qt[((size_t)(bh * Gg + (t / MID)) * HW + ij) * MID + (t % MID)];
    }
    // wave-local LDS: compiler inserts lgkmcnt; no block barrier needed for qs/pes/gsm/pp4

    const float4* qs4w = (const float4*)&qs[wave][0];

    // ---- pe scores: lanes = kl (<49), all 16 (v,g) ----
    if (lane < PP) {
        float pa[4][4];
        #pragma unroll
        for (int v = 0; v < 4; v++) { pa[v][0]=0; pa[v][1]=0; pa[v][2]=0; pa[v][3]=0; }
        for (int c = 0; c < 32; c++) {
            float q0 = qs[wave][0*MID+c], q1 = qs[wave][1*MID+c];
            float q2 = qs[wave][2*MID+c], q3 = qs[wave][3*MID+c];
            #pragma unroll
            for (int v = 0; v < 4; v++) {
                float pk = g_peT[(v * 32 + c) * PP + lane];
                pa[v][0] += pk * q0; pa[v][1] += pk * q1;
                pa[v][2] += pk * q2; pa[v][3] += pk * q3;
            }
        }
        #pragma unroll
        for (int v = 0; v < 4; v++)
            #pragma unroll
            for (int g = 0; g < 4; g++)
                pes[wave][(v * 4 + g) * PP + lane] = pa[v][g];
    }

    // ---- group scores: lane = vg*4+m ----
    {
        int g = (lane >> 2) & 3;
        float ga = 0.f;
        #pragma unroll
        for (int c = 0; c < 16; c++) ga += g_geT[c * 64 + lane] * qs[wave][g * MID + 32 + c];
        gsm[wave][lane] = ga;
    }

    // ---- per-lane geometry: lane = kl ----
    int kk = lane / Pp, ll = lane % Pp;           // valid for lane<49
    int cell = kk * 10 + ll + wave;               // tile cell for this wave's position
    bool vmask = (lane < PP) && ((unsigned)(i + kk - 3) < Hh) && ((unsigned)(j + ll - 3) < Ww);

    // ---- content: stage K[m] tile, accumulate acc[m][g] in registers ----
    float acc[4][4];
    #pragma unroll
    for (int m = 0; m < 4; m++) { acc[m][0]=0; acc[m][1]=0; acc[m][2]=0; acc[m][3]=0; }

    for (int m = 0; m < Gg; m++) {
        __syncthreads();                          // previous tile readers done
        for (int t = threadIdx.x; t < 840; t += 256) {
            int c4 = t % 12; int rem = t / 12;
            int xx = rem % 10, yy = rem / 10;
            int gy = i - 3 + yy, gx = j0 - 3 + xx;
            float4 val = {0.f, 0.f, 0.f, 0.f};
            if ((unsigned)gy < Hh && (unsigned)gx < Ww)
                val = *(const float4*)&Kbh[((size_t)(m * HW + gy * Ww + gx)) * MID + c4 * 4];
            *(float4*)&kvt[(yy * 10 + xx) * CSTR + c4 * 4] = val;
        }
        __syncthreads();
        if (lane < PP) {
            #pragma unroll
            for (int c4 = 0; c4 < 12; c4++) {
                float4 k4 = *(const float4*)&kvt[cell * CSTR + c4 * 4];
                #pragma unroll
                for (int g = 0; g < 4; g++) {
                    float4 q4 = qs4w[g * 12 + c4];
                    acc[m][g] += q4.x * k4.x + q4.y * k4.y + q4.z * k4.z + q4.w * k4.w;
                }
            }
        }
    }

    // ---- softmax over (m,kl) per (v,g); accumulate prob-sums over g ----
    float ppr[4][4];                              // [v][m]
    #pragma unroll
    for (int v = 0; v < 4; v++) { ppr[v][0]=0; ppr[v][1]=0; ppr[v][2]=0; ppr[v][3]=0; }
    int lclamp = lane < PP ? lane : 0;
    #pragma unroll
    for (int v = 0; v < 4; v++) {
        #pragma unroll
        for (int g = 0; g < 4; g++) {
            int vg = v * 4 + g;
            float pe_s = pes[wave][vg * PP + lclamp];
            float sv[4]; float mx = -INFINITY;
            #pragma unroll
            for (int m = 0; m < 4; m++) {
                float t = acc[m][g] + pe_s + gsm[wave][vg * 4 + m];
                sv[m] = vmask ? t : -INFINITY;
                mx = fmaxf(mx, sv[m]);
            }
            #pragma unroll
            for (int d = 32; d > 0; d >>= 1) mx = fmaxf(mx, __shfl_xor(mx, d, 64));
            float ex[4]; float ls = 0.f;
            #pragma unroll
            for (int m = 0; m < 4; m++) { ex[m] = __expf(sv[m] - mx); ls += ex[m]; }
            #pragma unroll
            for (int d = 32; d > 0; d >>= 1) ls += __shfl_xor(ls, d, 64);
            float rinv = 1.0f / ls;
            #pragma unroll
            for (int m = 0; m < 4; m++) ppr[v][m] += ex[m] * rinv;
        }
    }
    if (lane < PP) {
        #pragma unroll
        for (int m = 0; m < 4; m++)
            pp4[wave][m * PP + lane] = make_float4(ppr[0][m], ppr[1][m], ppr[2][m], ppr[3][m]);
    }

    // ---- PV: stage V[m] tile, lane = c (<48) computes o[v][c] ----
    float oacc[4] = {0.f, 0.f, 0.f, 0.f};
    int kklo = i < 3 ? 3 - i : 0, kkhi = i > Hh - 4 ? Hh + 2 - i : 6;
    int lllo = j < 3 ? 3 - j : 0, llhi = j > Ww - 4 ? Ww + 2 - j : 6;

    for (int m = 0; m < Gg; m++) {
        __syncthreads();                          // content(m=3)/PV(m-1) readers done
        for (int t = threadIdx.x; t < 840; t += 256) {
            int c4 = t % 12; int rem = t / 12;
            int xx = rem % 10, yy = rem / 10;
            int gy = i - 3 + yy, gx = j0 - 3 + xx;
            float4 val = {0.f, 0.f, 0.f, 0.f};
            if ((unsigned)gy < Hh && (unsigned)gx < Ww)
                val = *(const float4*)&Vbh[((size_t)(m * HW + gy * Ww + gx)) * MID + c4 * 4];
            *(float4*)&kvt[(yy * 10 + xx) * CSTR + c4 * 4] = val;
        }
        __syncthreads();
        if (lane < MID) {
            for (int kk2 = kklo; kk2 <= kkhi; kk2++) {
                #pragma unroll
                for (int ll2 = 0; ll2 < Pp; ll2++) {
                    if (ll2 < lllo || ll2 > llhi) continue;
                    float vv = kvt[(kk2 * 10 + ll2 + wave) * CSTR + lane];
                    float4 p4 = pp4[wave][m * PP + kk2 * Pp + ll2];
                    oacc[0] += p4.x * vv; oacc[1] += p4.y * vv;
                    oacc[2] += p4.z * vv; oacc[3] += p4.w * vv;
                }
            }
        }
    }

    if (lane < MID) {
        #pragma unroll
        for (int v = 0; v < 4; v++)
            Ot[((size_t)(b * Gg + v) * HW + ij) * OC + h * MID + lane] = oacc[v];
    }
}

// ---------------------------------------------------------------- kernel 3
__global__ __launch_bounds__(256) void outproj_kernel(const float* __restrict__ bout,
                                                      const float* __restrict__ ws,
                                                      float* __restrict__ out)
{
    __shared__ float ov[16 * 193];
    __shared__ float res[64 * 17];
    int tid = threadIdx.x;
    int p0 = blockIdx.x * 16;
    const float* Ot = ws + OOFF;

    for (int idx = tid; idx < 16 * OC; idx += 256) {
        int pl = idx / OC, t = idx % OC;
        ov[pl * 193 + t] = Ot[(size_t)(p0 + pl) * OC + t];
    }
    __syncthreads();

    int o = tid & 63, pg = tid >> 6;
    float a0 = bout[o], a1 = a0, a2 = a0, a3 = a0;
    for (int t = 0; t < OC; t++) {
        float w = g_WT2[t * 64 + o];
        a0 += w * ov[(pg     ) * 193 + t];
        a1 += w * ov[(pg +  4) * 193 + t];
        a2 += w * ov[(pg +  8) * 193 + t];
        a3 += w * ov[(pg + 12) * 193 + t];
    }
    res[o * 17 + pg     ] = a0;
    res[o * 17 + pg +  4] = a1;
    res[o * 17 + pg +  8] = a2;
    res[o * 17 + pg + 12] = a3;
    __syncthreads();

    for (int idx = tid; idx < 1024; idx += 256) {
        int o2 = idx >> 4, pl = idx & 15;
        int p = p0 + pl;
        int ij2 = p % HW; int bv = p / HW; int v = bv & 3; int bb = bv >> 2;
        out[((bb * COUT + o2) * Gg + v) * HW + ij2] = res[o2 * 17 + pl];
    }
}

// ---------------------------------------------------------------- launch
extern "C" void kernel_launch(void* const* d_in, const int* in_sizes, int n_in,
                              void* d_out, int out_size, void* d_ws, size_t ws_size,
                              hipStream_t stream)
{
    const float* x      = (const float*)d_in[0];
    const float* Wq     = (const float*)d_in[1];
    const float* bq     = (const float*)d_in[2];
    const float* Wk     = (const float*)d_in[3];
    const float* bk     = (const float*)d_in[4];
    const float* Wv     = (const float*)d_in[5];
    const float* bv     = (const float*)d_in[6];
    const float* Wout   = (const float*)d_in[7];
    const float* bout   = (const float*)d_in[8];
    const float* row_w1 = (const float*)d_in[9];
    const float* row_b1 = (const float*)d_in[10];
    const float* row_g  = (const float*)d_in[11];
    const float* row_bb = (const float*)d_in[12];
    const float* row_w2 = (const float*)d_in[13];
    const float* row_b2 = (const float*)d_in[14];
    const float* col_w1 = (const float*)d_in[15];
    const float* col_b1 = (const float*)d_in[16];
    const float* col_g  = (const float*)d_in[17];
    const float* col_bb = (const float*)d_in[18];
    const float* col_w2 = (const float*)d_in[19];
    const float* col_b2 = (const float*)d_in[20];
    const float* gemb   = (const float*)d_in[21];
    const float* ridx   = (const float*)d_in[22];
    const float* cidx   = (const float*)d_in[23];
    const int*   gidx   = (const int*)d_in[24];

    float* ws  = (float*)d_ws;
    float* out = (float*)d_out;

    qkvpe_kernel<<<Bb * Gg * Hh + 1, 192, 0, stream>>>(
        x, Wq, bq, Wk, bk, Wv, bv,
        row_w1, row_b1, row_g, row_bb, row_w2, row_b2,
        col_w1, col_b1, col_g, col_bb, col_w2, col_b2,
        ridx, cidx, gemb, gidx, Wout, ws);
    attn_kernel<<<Bb * NH * Hh * (Ww / 4), 256, 0, stream>>>(ws);
    outproj_kernel<<<Bb * Gg * HW / 16, 256, 0, stream>>>(bout, ws, out);
}